// Round 4
// baseline (298.926 us; speedup 1.0000x reference)
//
#include <hip/hip_runtime.h>
#include <hip/hip_bf16.h>
#include <math.h>

#define B_DIM 16
#define T_DIM 4096
#define D_DIM 512
#define R_DIM 256

#define TM 128          // rows (t) per block; wave owns 32 rows x 256 cols
#define BK 32           // k-chunk
#define NKCH (D_DIM/BK) // 16 k-chunks in blocked B layout

typedef __bf16 bf16x8 __attribute__((ext_vector_type(8)));
typedef float floatx4 __attribute__((ext_vector_type(4)));

// Replicate np.linspace(0, T-1, R).astype(int64) bit-exactly.
__device__ __forceinline__ int landmark_of(int r) {
    if (r >= 255) return 4095;
    const double step = 4095.0 / 255.0;
    return (int)((double)r * step);   // trunc toward zero == astype(int64)
}

__device__ __forceinline__ void split_bf16(float x, __bf16& h, __bf16& l) {
    h = (__bf16)x;
    l = (__bf16)(x - (float)h);
}

// ---- prep: normalized landmark rows of z, split hi/lo, blocked layout
// [b][kchunk 0..15][row 0..255][32 cols] -> main kernel loads B fragments
// directly from global in MFMA order (fully coalesced 1KB per wave-load). ----
__global__ void nystrom_prep_kernel(const float* __restrict__ z,
                                    __bf16* __restrict__ Khi, __bf16* __restrict__ Klo) {
    int blk = blockIdx.x;
    int b = blk >> 8;
    int r = blk & 255;
    int lane = threadIdx.x;            // 64 threads
    int lm = landmark_of(r);
    const float* src = z + ((size_t)b * T_DIM + lm) * D_DIM + lane * 8;
    float4 v0 = ((const float4*)src)[0];
    float4 v1 = ((const float4*)src)[1];
    float ss = v0.x*v0.x + v0.y*v0.y + v0.z*v0.z + v0.w*v0.w
             + v1.x*v1.x + v1.y*v1.y + v1.z*v1.z + v1.w*v1.w;
    #pragma unroll
    for (int off = 1; off < 64; off <<= 1) ss += __shfl_xor(ss, off, 64);
    float inv = 1.0f / fmaxf(sqrtf(ss), 1e-12f);
    float q[8] = {v0.x*inv, v0.y*inv, v0.z*inv, v0.w*inv,
                  v1.x*inv, v1.y*inv, v1.z*inv, v1.w*inv};
    bf16x8 oh, ol;
    #pragma unroll
    for (int j = 0; j < 8; j++) { __bf16 h, l; split_bf16(q[j], h, l); oh[j] = h; ol[j] = l; }
    size_t dst = (((size_t)b * NKCH + (lane >> 2)) * R_DIM + r) * BK + (size_t)(lane & 3) * 8;
    *(bf16x8*)(Khi + dst) = oh;
    *(bf16x8*)(Klo + dst) = ol;
}

// ---- main: barrier-free K-loop. A fp32 -> hi/lo regs; B frags direct from
// global (blocked layout) with register ping-pong prefetch; 3-pass split MFMA. ----
__global__ __launch_bounds__(256, 2)
void nystrom_main_kernel(const float* __restrict__ z,
                         const __bf16* __restrict__ Khi, const __bf16* __restrict__ Klo,
                         const float* __restrict__ gw, const float* __restrict__ ta,
                         float* __restrict__ out) {
    __shared__ float rnorm_s[TM];
    __shared__ int   lmtab[R_DIM];
    __shared__ float elmtab[R_DIM];

    const int tid  = threadIdx.x;
    const int b    = blockIdx.y;
    const int t0   = blockIdx.x * TM;
    const int lane = tid & 63;
    const int wv   = tid >> 6;
    const int quad = lane >> 4;
    const int ln   = lane & 15;

    // --- scalars ---
    float g0 = gw[0], g1 = gw[1], g2 = gw[2];
    float gm = fmaxf(g0, fmaxf(g1, g2));
    float e0 = expf(g0 - gm), e1 = expf(g1 - gm), e2 = expf(g2 - gm);
    float esum = e0 + e1 + e2;
    float al0 = e0 / esum, al1 = e1 / esum, al2 = e2 / esum;
    float ax = ta[0];
    float a_td = (ax > 20.f) ? ax : log1pf(expf(ax));

    {
        int lm = landmark_of(tid);
        lmtab[tid] = lm;
        elmtab[tid] = expf(a_td * (float)lm * (1.0f / 4096.0f));
    }

    // A: lane loads rows (t0 + wv*32 + mi*16 + ln), cols kt*32 + quad*8 .. +7
    const float* za = z + ((size_t)b * T_DIM + t0 + wv * 32 + ln) * D_DIM + quad * 8;
    // B: blocked layout; frag(ni) elem offset = ni*512 + ln*32 + quad*8
    const size_t kbase = (size_t)b * NKCH * R_DIM * BK;
    const __bf16* KbH = Khi + kbase;
    const __bf16* KbL = Klo + kbase;
    const int bcol = ln * BK + quad * 8;

    floatx4 acc[2][16];
    #pragma unroll
    for (int i = 0; i < 2; i++)
        #pragma unroll
        for (int j = 0; j < 16; j++) acc[i][j] = (floatx4){0.f, 0.f, 0.f, 0.f};
    float ssq0 = 0.f, ssq1 = 0.f;

    // ---- preload A (kt=0) and B quarter 0 ----
    float4 a00 = *(const float4*)(za);
    float4 a01 = *(const float4*)(za + 4);
    float4 a10 = *(const float4*)(za + 16 * D_DIM);
    float4 a11 = *(const float4*)(za + 16 * D_DIM + 4);

    bf16x8 bh[8], bl[8];   // ping-pong: [0..3] / [4..7]
    #pragma unroll
    for (int j = 0; j < 4; j++) {
        bh[j] = *(const bf16x8*)(KbH + j * 512 + bcol);
        bl[j] = *(const bf16x8*)(KbL + j * 512 + bcol);
    }

    #pragma unroll 1
    for (int kt = 0; kt < NKCH; kt++) {
        // --- convert A for this kt (regs already loaded) ---
        bf16x8 afh0, afl0, afh1, afl1;
        {
            float av[16] = {a00.x,a00.y,a00.z,a00.w, a01.x,a01.y,a01.z,a01.w,
                            a10.x,a10.y,a10.z,a10.w, a11.x,a11.y,a11.z,a11.w};
            #pragma unroll
            for (int j = 0; j < 8; j++) {
                ssq0 += av[j] * av[j];
                __bf16 h, l; split_bf16(av[j], h, l); afh0[j] = h; afl0[j] = l;
            }
            #pragma unroll
            for (int j = 0; j < 8; j++) {
                ssq1 += av[8 + j] * av[8 + j];
                __bf16 h, l; split_bf16(av[8 + j], h, l); afh1[j] = h; afl1[j] = l;
            }
        }
        // --- prefetch A for kt+1 (one full iteration of latency cover) ---
        if (kt + 1 < NKCH) {
            const float* zp = za + (kt + 1) * BK;
            a00 = *(const float4*)(zp);
            a01 = *(const float4*)(zp + 4);
            a10 = *(const float4*)(zp + 16 * D_DIM);
            a11 = *(const float4*)(zp + 16 * D_DIM + 4);
        }
        // --- 4 quarters of 4 ni; prefetch next quarter while MFMA-ing current ---
        #pragma unroll
        for (int q = 0; q < 4; q++) {
            const int cb = (q & 1) * 4;       // current buffer
            const int nb = 4 - cb;            // next buffer
            int nq = q + 1, nkt = kt;
            if (nq == 4) { nq = 0; nkt = kt + 1; }
            if (nkt < NKCH) {
                const __bf16* ph = KbH + (size_t)nkt * 8192 + nq * 2048 + bcol;
                const __bf16* pl = KbL + (size_t)nkt * 8192 + nq * 2048 + bcol;
                #pragma unroll
                for (int j = 0; j < 4; j++) {
                    bh[nb + j] = *(const bf16x8*)(ph + j * 512);
                    bl[nb + j] = *(const bf16x8*)(pl + j * 512);
                }
            }
            #pragma unroll
            for (int j = 0; j < 4; j++) {
                const int ni = q * 4 + j;
                acc[0][ni] = __builtin_amdgcn_mfma_f32_16x16x32_bf16(afh0, bh[cb + j], acc[0][ni], 0, 0, 0);
                acc[0][ni] = __builtin_amdgcn_mfma_f32_16x16x32_bf16(afh0, bl[cb + j], acc[0][ni], 0, 0, 0);
                acc[0][ni] = __builtin_amdgcn_mfma_f32_16x16x32_bf16(afl0, bh[cb + j], acc[0][ni], 0, 0, 0);
                acc[1][ni] = __builtin_amdgcn_mfma_f32_16x16x32_bf16(afh1, bh[cb + j], acc[1][ni], 0, 0, 0);
                acc[1][ni] = __builtin_amdgcn_mfma_f32_16x16x32_bf16(afh1, bl[cb + j], acc[1][ni], 0, 0, 0);
                acc[1][ni] = __builtin_amdgcn_mfma_f32_16x16x32_bf16(afl1, bh[cb + j], acc[1][ni], 0, 0, 0);
            }
        }
    }

    // --- row norms: reduce ssq over quads (each quad held 8 of every 32 cols) ---
    ssq0 += __shfl_xor(ssq0, 16, 64); ssq0 += __shfl_xor(ssq0, 32, 64);
    ssq1 += __shfl_xor(ssq1, 16, 64); ssq1 += __shfl_xor(ssq1, 32, 64);
    if (quad == 0) {
        rnorm_s[wv * 32 + ln]      = 1.0f / fmaxf(sqrtf(ssq0), 1e-12f);
        rnorm_s[wv * 32 + 16 + ln] = 1.0f / fmaxf(sqrtf(ssq1), 1e-12f);
    }
    __syncthreads();   // also orders lmtab/elmtab writes before reads below

    // per-lane landmark columns (r = ni*16 + ln)
    int   lm_r[16];
    float elm_r[16];
    #pragma unroll
    for (int ni = 0; ni < 16; ni++) {
        lm_r[ni]  = lmtab[ni * 16 + ln];
        elm_r[ni] = elmtab[ni * 16 + ln];
    }

    // --- polynomial + mask + decay; in-wave row-sum; store ---
    float* ob = out + ((size_t)b * T_DIM + t0 + wv * 32) * 257;
    #pragma unroll
    for (int mi = 0; mi < 2; mi++) {
        #pragma unroll
        for (int reg = 0; reg < 4; reg++) {
            const int row = mi * 16 + quad * 4 + reg;   // within wave's 32 rows
            const int t = t0 + wv * 32 + row;
            const float rn = rnorm_s[wv * 32 + row];
            const float e_t = expf(-a_td * (float)t * (1.0f / 4096.0f));
            float s = 0.f;
            #pragma unroll
            for (int ni = 0; ni < 16; ni++) {
                float phi = 0.f;
                if (lm_r[ni] < t) {
                    float c  = acc[mi][ni][reg] * rn;
                    float c2 = c * c;
                    float P1 = 0.5f * (1.f + c);
                    float P2 = 0.5f * (3.f * c2 - 1.f);
                    float P3 = 0.5f * (5.f * c2 * c - 3.f * c);
                    float p  = al0 * P1 + al1 * P2 + al2 * P3;
                    phi = p * e_t * elm_r[ni];
                }
                acc[mi][ni][reg] = phi;
                s += phi;
            }
            s += __shfl_xor(s, 1, 64);
            s += __shfl_xor(s, 2, 64);
            s += __shfl_xor(s, 4, 64);
            s += __shfl_xor(s, 8, 64);
            const float inv = 1.0f / fmaxf(s, 1e-6f);
            #pragma unroll
            for (int ni = 0; ni < 16; ni++) {
                ob[(size_t)row * 257 + ni * 16 + ln] = acc[mi][ni][reg] * inv;
            }
        }
    }
    if (tid < TM) out[((size_t)b * T_DIM + t0 + tid) * 257 + 256] = 1.0f;
}

extern "C" void kernel_launch(void* const* d_in, const int* in_sizes, int n_in,
                              void* d_out, int out_size, void* d_ws, size_t ws_size,
                              hipStream_t stream) {
    const float* z  = (const float*)d_in[0];
    const float* gw = (const float*)d_in[1];
    const float* ta = (const float*)d_in[2];
    float* out = (float*)d_out;
    __bf16* Khi = (__bf16*)d_ws;                                               // 4 MiB
    __bf16* Klo = (__bf16*)((char*)d_ws + (size_t)B_DIM * R_DIM * D_DIM * 2);  // +4 MiB

    nystrom_prep_kernel<<<dim3(B_DIM * R_DIM), 64, 0, stream>>>(z, Khi, Klo);
    nystrom_main_kernel<<<dim3(T_DIM / TM, B_DIM), 256, 0, stream>>>(z, Khi, Klo, gw, ta, out);
}

// Round 5
// 270.174 us; speedup vs baseline: 1.1064x; 1.1064x over previous
//
#include <hip/hip_runtime.h>
#include <hip/hip_bf16.h>
#include <math.h>

#define B_DIM 16
#define T_DIM 4096
#define D_DIM 512
#define R_DIM 256

#define TM 64           // rows per block; 4 waves, wave = 64 rows x 64 cols
#define BK 32           // k-chunk
#define NKCH 16
#define CHUNK 32768     // blob bytes per (b,kchunk): hi 16K | lo 16K, swizzled image

typedef __bf16 bf16x8 __attribute__((ext_vector_type(8)));
typedef float floatx4 __attribute__((ext_vector_type(4)));

// Replicate np.linspace(0, T-1, R).astype(int64) bit-exactly.
__device__ __forceinline__ int landmark_of(int r) {
    if (r >= 255) return 4095;
    const double step = 4095.0 / 255.0;
    return (int)((double)r * step);
}

__device__ __forceinline__ void split_bf16(float x, __bf16& h, __bf16& l) {
    h = (__bf16)x;
    l = (__bf16)(x - (float)h);
}

__device__ __forceinline__ void async_copy16(const void* g, void* l) {
    __builtin_amdgcn_global_load_lds(
        (const __attribute__((address_space(1))) unsigned int*)g,
        (__attribute__((address_space(3))) unsigned int*)l, 16, 0, 0);
}

// ---- prep: normalized landmark rows, split hi/lo, written as swizzled LDS
// images: chunk(b,kc) = [hi: r*64 + 16*((g+r)&3) | lo: +16384], r=0..255, g=0..3.
__global__ void nystrom_prep_kernel(const float* __restrict__ z, char* __restrict__ blob) {
    int blk = blockIdx.x;
    int b = blk >> 8;
    int r = blk & 255;
    int lane = threadIdx.x;            // 64 threads
    int lm = landmark_of(r);
    const float* src = z + ((size_t)b * T_DIM + lm) * D_DIM + lane * 8;
    float4 v0 = ((const float4*)src)[0];
    float4 v1 = ((const float4*)src)[1];
    float ss = v0.x*v0.x + v0.y*v0.y + v0.z*v0.z + v0.w*v0.w
             + v1.x*v1.x + v1.y*v1.y + v1.z*v1.z + v1.w*v1.w;
    #pragma unroll
    for (int off = 1; off < 64; off <<= 1) ss += __shfl_xor(ss, off, 64);
    float inv = 1.0f / fmaxf(sqrtf(ss), 1e-12f);
    float qv[8] = {v0.x*inv, v0.y*inv, v0.z*inv, v0.w*inv,
                   v1.x*inv, v1.y*inv, v1.z*inv, v1.w*inv};
    bf16x8 oh, ol;
    #pragma unroll
    for (int j = 0; j < 8; j++) { __bf16 h, l; split_bf16(qv[j], h, l); oh[j] = h; ol[j] = l; }
    int kc = lane >> 2, g = lane & 3;
    char* dst = blob + ((size_t)(b * NKCH + kc)) * CHUNK + r * 64 + 16 * ((g + r) & 3);
    *(bf16x8*)dst = oh;
    *(bf16x8*)(dst + 16384) = ol;
}

// ---- main: 2-barrier K-loop; B via async DMA image copy, A via reg prefetch
// (issued at top of MFMA phase) + single-convert staging; 3-pass split MFMA. ----
__global__ __launch_bounds__(256, 3)
void nystrom_main_kernel(const float* __restrict__ z, const char* __restrict__ blob,
                         const float* __restrict__ gw, const float* __restrict__ ta,
                         float* __restrict__ out) {
    __shared__ __attribute__((aligned(16))) char smem[40960];
    __bf16* Bs = (__bf16*)smem;                    // 32K: hi [0,16K) lo [16K,32K)
    char*   Asb = smem + 32768;                    // 8K: hi [0,4K) lo [4K,8K)
    float* rnorm_s = (float*)(smem + 32768);       // alias, used after final barrier
    float* rspart  = (float*)(smem + 32768 + 256); // [wv][64] = 1024 B

    const int tid  = threadIdx.x;
    const int b    = blockIdx.y;
    const int t0   = blockIdx.x * TM;
    const int lane = tid & 63;
    const int wv   = tid >> 6;
    const int q    = lane >> 4;
    const int ln   = lane & 15;

    // --- scalars ---
    float g0 = gw[0], g1 = gw[1], g2 = gw[2];
    float gm = fmaxf(g0, fmaxf(g1, g2));
    float e0 = expf(g0 - gm), e1 = expf(g1 - gm), e2 = expf(g2 - gm);
    float esum = e0 + e1 + e2;
    float al0 = e0 / esum, al1 = e1 / esum, al2 = e2 / esum;
    float ax = ta[0];
    float a_td = (ax > 20.f) ? ax : log1pf(expf(ax));

    // --- A staging map: 4 threads/row, 8 fp32 each ---
    const int arow = tid >> 2, ag = tid & 3;
    const float* zsrc = z + ((size_t)b * T_DIM + t0 + arow) * D_DIM + ag * 8;
    char* awh = Asb + arow * 64 + 16 * ((ag + arow) & 3);
    char* awl = awh + 4096;

    // --- B DMA source (swizzled image) ---
    const char* bsrc0 = blob + (size_t)(b * NKCH) * CHUNK + wv * 8192 + lane * 16;
    char* bdst0 = smem + wv * 8192;   // wave-uniform; HW adds lane*16

    floatx4 acc[4][4];
    #pragma unroll
    for (int i = 0; i < 4; i++)
        #pragma unroll
        for (int j = 0; j < 4; j++) acc[i][j] = (floatx4){0.f, 0.f, 0.f, 0.f};
    float ssq = 0.0f;

    // preload A (kt=0)
    float4 pa0 = *(const float4*)(zsrc);
    float4 pa1 = *(const float4*)(zsrc + 4);

    #pragma unroll 1
    for (int kt = 0; kt < NKCH; kt++) {
        // --- staging: convert A (regs loaded last phase), write LDS; launch B DMA ---
        {
            float av[8] = {pa0.x, pa0.y, pa0.z, pa0.w, pa1.x, pa1.y, pa1.z, pa1.w};
            bf16x8 h8, l8;
            #pragma unroll
            for (int j = 0; j < 8; j++) {
                ssq += av[j] * av[j];
                __bf16 h, l; split_bf16(av[j], h, l); h8[j] = h; l8[j] = l;
            }
            *(bf16x8*)awh = h8;
            *(bf16x8*)awl = l8;
        }
        {
            const char* bs = bsrc0 + (size_t)kt * CHUNK;
            #pragma unroll
            for (int i = 0; i < 8; i++)
                async_copy16(bs + i * 1024, bdst0 + i * 1024);
        }
        __syncthreads();   // staging visible (ds writes + DMA drained)

        // --- A prefetch for kt+1: in flight across the MFMA phase ---
        if (kt + 1 < NKCH) {
            const float* zp = zsrc + (kt + 1) * BK;
            pa0 = *(const float4*)(zp);
            pa1 = *(const float4*)(zp + 4);
        }

        // --- MFMA: 48 per wave (4x4 tiles, 3-pass split) ---
        {
            const int rot = 16 * ((q + ln) & 3);
            bf16x8 bh[4], bl[4];
            #pragma unroll
            for (int ni = 0; ni < 4; ni++) {
                const char* p = (const char*)Bs + (wv * 64 + ni * 16 + ln) * 64 + rot;
                bh[ni] = *(const bf16x8*)p;
                bl[ni] = *(const bf16x8*)(p + 16384);
            }
            #pragma unroll
            for (int mi = 0; mi < 4; mi++) {
                const char* pa = Asb + (mi * 16 + ln) * 64 + rot;
                bf16x8 ah = *(const bf16x8*)pa;
                bf16x8 al = *(const bf16x8*)(pa + 4096);
                #pragma unroll
                for (int ni = 0; ni < 4; ni++) {
                    acc[mi][ni] = __builtin_amdgcn_mfma_f32_16x16x32_bf16(ah, bh[ni], acc[mi][ni], 0, 0, 0);
                    acc[mi][ni] = __builtin_amdgcn_mfma_f32_16x16x32_bf16(ah, bl[ni], acc[mi][ni], 0, 0, 0);
                    acc[mi][ni] = __builtin_amdgcn_mfma_f32_16x16x32_bf16(al, bh[ni], acc[mi][ni], 0, 0, 0);
                }
            }
        }
        __syncthreads();   // reads done; LDS reusable next iter (and by epilogue)
    }

    // --- row norms: 4 staging threads per row are lanes differing in bits 0..1 ---
    ssq += __shfl_xor(ssq, 1, 64);
    ssq += __shfl_xor(ssq, 2, 64);
    if (ag == 0) rnorm_s[arow] = 1.0f / fmaxf(sqrtf(ssq), 1e-12f);
    __syncthreads();

    // per-lane landmark columns (cols wv*64 + ni*16 + ln)
    int   lm_r[4];
    float elm_r[4];
    #pragma unroll
    for (int ni = 0; ni < 4; ni++) {
        int r = wv * 64 + ni * 16 + ln;
        lm_r[ni]  = landmark_of(r);
        elm_r[ni] = expf(a_td * (float)lm_r[ni] * (1.0f / 4096.0f));
    }

    // --- polynomial + mask + decay; per-wave 64-col partial row sums ---
    #pragma unroll
    for (int mi = 0; mi < 4; mi++) {
        #pragma unroll
        for (int reg = 0; reg < 4; reg++) {
            const int row = mi * 16 + q * 4 + reg;
            const int t = t0 + row;
            const float rn = rnorm_s[row];
            const float e_t = expf(-a_td * (float)t * (1.0f / 4096.0f));
            float s = 0.f;
            #pragma unroll
            for (int ni = 0; ni < 4; ni++) {
                float phi = 0.f;
                if (lm_r[ni] < t) {
                    float c  = acc[mi][ni][reg] * rn;
                    float c2 = c * c;
                    float P1 = 0.5f * (1.f + c);
                    float P2 = 0.5f * (3.f * c2 - 1.f);
                    float P3 = 0.5f * (5.f * c2 * c - 3.f * c);
                    float p  = al0 * P1 + al1 * P2 + al2 * P3;
                    phi = p * e_t * elm_r[ni];
                }
                acc[mi][ni][reg] = phi;
                s += phi;
            }
            s += __shfl_xor(s, 1, 64);
            s += __shfl_xor(s, 2, 64);
            s += __shfl_xor(s, 4, 64);
            s += __shfl_xor(s, 8, 64);
            if (ln == 0) rspart[wv * 64 + row] = s;
        }
    }
    __syncthreads();

    // --- normalize + store ---
    float* ob = out + ((size_t)b * T_DIM + t0) * 257;
    #pragma unroll
    for (int mi = 0; mi < 4; mi++) {
        #pragma unroll
        for (int reg = 0; reg < 4; reg++) {
            const int row = mi * 16 + q * 4 + reg;
            float rs = rspart[row] + rspart[64 + row] + rspart[128 + row] + rspart[192 + row];
            float inv = 1.0f / fmaxf(rs, 1e-6f);
            #pragma unroll
            for (int ni = 0; ni < 4; ni++) {
                ob[(size_t)row * 257 + wv * 64 + ni * 16 + ln] = acc[mi][ni][reg] * inv;
            }
        }
    }
    if (tid < TM) ob[(size_t)tid * 257 + 256] = 1.0f;
}

extern "C" void kernel_launch(void* const* d_in, const int* in_sizes, int n_in,
                              void* d_out, int out_size, void* d_ws, size_t ws_size,
                              hipStream_t stream) {
    const float* z  = (const float*)d_in[0];
    const float* gw = (const float*)d_in[1];
    const float* ta = (const float*)d_in[2];
    float* out = (float*)d_out;
    char* blob = (char*)d_ws;   // 16*16*32768 = 8 MiB

    nystrom_prep_kernel<<<dim3(B_DIM * R_DIM), 64, 0, stream>>>(z, blob);
    nystrom_main_kernel<<<dim3(T_DIM / TM, B_DIM), 256, 0, stream>>>(z, blob, gw, ta, out);
}

// Round 6
// 257.178 us; speedup vs baseline: 1.1623x; 1.0505x over previous
//
#include <hip/hip_runtime.h>
#include <hip/hip_bf16.h>
#include <math.h>

#define B_DIM 16
#define T_DIM 4096
#define D_DIM 512
#define R_DIM 256

#define TM 64           // rows per block; 4 waves, wave = 64 rows x 64 cols
#define NKCH 16         // k-chunks of 32
#define CHUNK 32768     // blob bytes per (b,kchunk): hi 16K | lo 16K, swizzled LDS image

typedef __bf16 bf16x8 __attribute__((ext_vector_type(8)));
typedef float floatx4 __attribute__((ext_vector_type(4)));

// Replicate np.linspace(0, T-1, R).astype(int64) bit-exactly.
__device__ __forceinline__ int landmark_of(int r) {
    if (r >= 255) return 4095;
    const double step = 4095.0 / 255.0;
    return (int)((double)r * step);
}

__device__ __forceinline__ void split_bf16(float x, __bf16& h, __bf16& l) {
    h = (__bf16)x;
    l = (__bf16)(x - (float)h);
}

// Bank-conflict-free granule swizzle: rows 1,2,3 AND 4,8,12 apart get distinct
// granules -> every b128 access is exactly 2 lanes/bank-group (free).
__device__ __forceinline__ int swz(int row, int g) {
    return 16 * ((g + (row & 3) + ((row >> 2) & 3)) & 3);
}

__device__ __forceinline__ void async_copy16(const void* g, void* l) {
    __builtin_amdgcn_global_load_lds(
        (const __attribute__((address_space(1))) unsigned int*)g,
        (__attribute__((address_space(3))) unsigned int*)l, 16, 0, 0);
}

// ---- prep: normalized landmark rows, split hi/lo, written as swizzled LDS
// images: chunk(b,kc): hi at r*64 + swz(r,g), lo at +16384. ----
__global__ void nystrom_prep_kernel(const float* __restrict__ z, char* __restrict__ blob) {
    int blk = blockIdx.x;
    int b = blk >> 8;
    int r = blk & 255;
    int lane = threadIdx.x;            // 64 threads
    int lm = landmark_of(r);
    const float* src = z + ((size_t)b * T_DIM + lm) * D_DIM + lane * 8;
    float4 v0 = ((const float4*)src)[0];
    float4 v1 = ((const float4*)src)[1];
    float ss = v0.x*v0.x + v0.y*v0.y + v0.z*v0.z + v0.w*v0.w
             + v1.x*v1.x + v1.y*v1.y + v1.z*v1.z + v1.w*v1.w;
    #pragma unroll
    for (int off = 1; off < 64; off <<= 1) ss += __shfl_xor(ss, off, 64);
    float inv = 1.0f / fmaxf(sqrtf(ss), 1e-12f);
    float qv[8] = {v0.x*inv, v0.y*inv, v0.z*inv, v0.w*inv,
                   v1.x*inv, v1.y*inv, v1.z*inv, v1.w*inv};
    bf16x8 oh, ol;
    #pragma unroll
    for (int j = 0; j < 8; j++) { __bf16 h, l; split_bf16(qv[j], h, l); oh[j] = h; ol[j] = l; }
    int kc = lane >> 2, g = lane & 3;
    char* dst = blob + ((size_t)(b * NKCH + kc)) * CHUNK + r * 64 + swz(r, g);
    *(bf16x8*)dst = oh;
    *(bf16x8*)(dst + 16384) = ol;
}

__device__ __forceinline__ void stage_a(float4 v0, float4 v1, char* abuf, int awoff, float& ssq) {
    float av[8] = {v0.x, v0.y, v0.z, v0.w, v1.x, v1.y, v1.z, v1.w};
    bf16x8 h8, l8;
    #pragma unroll
    for (int j = 0; j < 8; j++) {
        ssq += av[j] * av[j];
        __bf16 h, l; split_bf16(av[j], h, l); h8[j] = h; l8[j] = l;
    }
    *(bf16x8*)(abuf + awoff) = h8;
    *(bf16x8*)(abuf + awoff + 4096) = l8;
}

__device__ __forceinline__ void mfma_phase(const char* bB, const char* bA,
                                           int wv, int ln, int rot, floatx4 (&acc)[4][4]) {
    bf16x8 bh[4], bl[4];
    #pragma unroll
    for (int ni = 0; ni < 4; ni++) {
        const char* p = bB + (wv * 64 + ni * 16 + ln) * 64 + rot;
        bh[ni] = *(const bf16x8*)p;
        bl[ni] = *(const bf16x8*)(p + 16384);
    }
    #pragma unroll
    for (int mi = 0; mi < 4; mi++) {
        const char* pA = bA + (mi * 16 + ln) * 64 + rot;
        bf16x8 ah = *(const bf16x8*)pA;
        bf16x8 al = *(const bf16x8*)(pA + 4096);
        #pragma unroll
        for (int ni = 0; ni < 4; ni++) {
            acc[mi][ni] = __builtin_amdgcn_mfma_f32_16x16x32_bf16(ah, bh[ni], acc[mi][ni], 0, 0, 0);
            acc[mi][ni] = __builtin_amdgcn_mfma_f32_16x16x32_bf16(ah, bl[ni], acc[mi][ni], 0, 0, 0);
            acc[mi][ni] = __builtin_amdgcn_mfma_f32_16x16x32_bf16(al, bh[ni], acc[mi][ni], 0, 0, 0);
        }
    }
}

// ---- main: single-barrier pipelined K-loop. LDS double-buffered A and B;
// DMA B(kt+2) issued right AFTER barrier(kt) so it is in flight for a full
// MFMA phase before barrier(kt+1) drains it; A global loads likewise covered. ----
__global__ __launch_bounds__(256, 2)
void nystrom_main_kernel(const float* __restrict__ z, const char* __restrict__ blob,
                         const float* __restrict__ gw, const float* __restrict__ ta,
                         float* __restrict__ out) {
    // [0,32K) Bbuf0 | [32K,64K) Bbuf1 | [64K,72K) Abuf0 | [72K,80K) Abuf1
    __shared__ __attribute__((aligned(16))) char smem[81920];
    float* rnorm_s = (float*)(smem + 65536);          // epilogue alias (Abuf0, dead)
    float* rspart  = (float*)(smem + 65536 + 256);

    const int tid  = threadIdx.x;
    const int b    = blockIdx.y;
    const int t0   = blockIdx.x * TM;
    const int lane = tid & 63;
    const int wv   = tid >> 6;
    const int q    = lane >> 4;
    const int ln   = lane & 15;

    // --- scalars ---
    float g0 = gw[0], g1 = gw[1], g2 = gw[2];
    float gm = fmaxf(g0, fmaxf(g1, g2));
    float e0 = expf(g0 - gm), e1 = expf(g1 - gm), e2 = expf(g2 - gm);
    float esum = e0 + e1 + e2;
    float al0 = e0 / esum, al1 = e1 / esum, al2 = e2 / esum;
    float ax = ta[0];
    float a_td = (ax > 20.f) ? ax : log1pf(expf(ax));

    // --- A staging map: 4 threads/row, 8 fp32 each ---
    const int arow = tid >> 2, ag = tid & 3;
    const float* zsrc = z + ((size_t)b * T_DIM + t0 + arow) * D_DIM + ag * 8;
    const int awoff = arow * 64 + swz(arow, ag);

    // --- B DMA src/dst (image copy) ---
    const char* bsrc = blob + (size_t)(b * NKCH) * CHUNK + wv * 8192 + lane * 16;
    const int bdoff = wv * 8192;

    const int rot = swz(ln, q);   // frag rows are 16-aligned + ln

    floatx4 acc[4][4];
    #pragma unroll
    for (int i = 0; i < 4; i++)
        #pragma unroll
        for (int j = 0; j < 4; j++) acc[i][j] = (floatx4){0.f, 0.f, 0.f, 0.f};
    float ssq = 0.0f;

    // ---- prologue: DMA B(0); load A(0),A(1); stage A(0); barrier; DMA B(1) ----
    #pragma unroll
    for (int i = 0; i < 8; i++) async_copy16(bsrc + i * 1024, smem + bdoff + i * 1024);
    float4 pa0a = *(const float4*)(zsrc);
    float4 pa0b = *(const float4*)(zsrc + 4);
    float4 pa1a = *(const float4*)(zsrc + 32);
    float4 pa1b = *(const float4*)(zsrc + 36);
    stage_a(pa0a, pa0b, smem + 65536, awoff, ssq);
    __syncthreads();
    #pragma unroll
    for (int i = 0; i < 8; i++) async_copy16(bsrc + CHUNK + i * 1024, smem + 32768 + bdoff + i * 1024);

    #pragma unroll 1
    for (int kt2 = 0; kt2 < 8; kt2++) {
        const int kt = kt2 * 2;
        const bool more = (kt2 < 7);
        // ---- even step kt: consume (Abuf0, Bbuf0) ----
        stage_a(pa1a, pa1b, smem + 65536 + 8192, awoff, ssq);          // A(kt+1) -> Abuf1
        if (more) {
            const float* zp = zsrc + (kt + 2) * 32;                     // A(kt+2) in flight over MFMA
            pa0a = *(const float4*)(zp);
            pa0b = *(const float4*)(zp + 4);
        }
        mfma_phase(smem, smem + 65536, wv, ln, rot, acc);
        __syncthreads();                                                // drains DMA B(kt+1) (covered)
        if (more) {
            const char* s2 = bsrc + (size_t)(kt + 2) * CHUNK;           // DMA B(kt+2) -> Bbuf0 (freed)
            #pragma unroll
            for (int i = 0; i < 8; i++) async_copy16(s2 + i * 1024, smem + bdoff + i * 1024);
        }
        // ---- odd step kt+1: consume (Abuf1, Bbuf1) ----
        if (more) stage_a(pa0a, pa0b, smem + 65536, awoff, ssq);        // A(kt+2) -> Abuf0
        if (more) {
            const float* zp = zsrc + (kt + 3) * 32;                     // A(kt+3)
            pa1a = *(const float4*)(zp);
            pa1b = *(const float4*)(zp + 4);
        }
        mfma_phase(smem + 32768, smem + 65536 + 8192, wv, ln, rot, acc);
        __syncthreads();                                                // drains DMA B(kt+2) (covered)
        if (more) {
            const char* s3 = bsrc + (size_t)(kt + 3) * CHUNK;           // DMA B(kt+3) -> Bbuf1 (freed)
            #pragma unroll
            for (int i = 0; i < 8; i++) async_copy16(s3 + i * 1024, smem + 32768 + bdoff + i * 1024);
        }
    }

    // --- row norms: 4 staging threads per row differ in lane bits 0..1 ---
    ssq += __shfl_xor(ssq, 1, 64);
    ssq += __shfl_xor(ssq, 2, 64);
    if (ag == 0) rnorm_s[arow] = 1.0f / fmaxf(sqrtf(ssq), 1e-12f);
    __syncthreads();

    // per-lane landmark columns (cols wv*64 + ni*16 + ln)
    int   lm_r[4];
    float elm_r[4];
    #pragma unroll
    for (int ni = 0; ni < 4; ni++) {
        int r = wv * 64 + ni * 16 + ln;
        lm_r[ni]  = landmark_of(r);
        elm_r[ni] = expf(a_td * (float)lm_r[ni] * (1.0f / 4096.0f));
    }

    // --- polynomial + mask + decay; per-wave 64-col partial row sums ---
    #pragma unroll
    for (int mi = 0; mi < 4; mi++) {
        #pragma unroll
        for (int reg = 0; reg < 4; reg++) {
            const int row = mi * 16 + q * 4 + reg;
            const int t = t0 + row;
            const float rn = rnorm_s[row];
            const float e_t = expf(-a_td * (float)t * (1.0f / 4096.0f));
            float s = 0.f;
            #pragma unroll
            for (int ni = 0; ni < 4; ni++) {
                float phi = 0.f;
                if (lm_r[ni] < t) {
                    float c  = acc[mi][ni][reg] * rn;
                    float c2 = c * c;
                    float P1 = 0.5f * (1.f + c);
                    float P2 = 0.5f * (3.f * c2 - 1.f);
                    float P3 = 0.5f * (5.f * c2 * c - 3.f * c);
                    float p  = al0 * P1 + al1 * P2 + al2 * P3;
                    phi = p * e_t * elm_r[ni];
                }
                acc[mi][ni][reg] = phi;
                s += phi;
            }
            s += __shfl_xor(s, 1, 64);
            s += __shfl_xor(s, 2, 64);
            s += __shfl_xor(s, 4, 64);
            s += __shfl_xor(s, 8, 64);
            if (ln == 0) rspart[wv * 64 + row] = s;
        }
    }
    __syncthreads();

    // --- normalize + store ---
    float* ob = out + ((size_t)b * T_DIM + t0) * 257;
    #pragma unroll
    for (int mi = 0; mi < 4; mi++) {
        #pragma unroll
        for (int reg = 0; reg < 4; reg++) {
            const int row = mi * 16 + q * 4 + reg;
            float rs = rspart[row] + rspart[64 + row] + rspart[128 + row] + rspart[192 + row];
            float inv = 1.0f / fmaxf(rs, 1e-6f);
            #pragma unroll
            for (int ni = 0; ni < 4; ni++) {
                ob[(size_t)row * 257 + wv * 64 + ni * 16 + ln] = acc[mi][ni][reg] * inv;
            }
        }
    }
    if (tid < TM) ob[(size_t)tid * 257 + 256] = 1.0f;
}

extern "C" void kernel_launch(void* const* d_in, const int* in_sizes, int n_in,
                              void* d_out, int out_size, void* d_ws, size_t ws_size,
                              hipStream_t stream) {
    const float* z  = (const float*)d_in[0];
    const float* gw = (const float*)d_in[1];
    const float* ta = (const float*)d_in[2];
    float* out = (float*)d_out;
    char* blob = (char*)d_ws;   // 16*16*32768 = 8 MiB

    nystrom_prep_kernel<<<dim3(B_DIM * R_DIM), 64, 0, stream>>>(z, blob);
    nystrom_main_kernel<<<dim3(T_DIM / TM, B_DIM), 256, 0, stream>>>(z, blob, gw, ta, out);
}